// Round 12
// baseline (300.448 us; speedup 1.0000x reference)
//
#include <hip/hip_runtime.h>
#include <hip/hip_bf16.h>
#include <math.h>

#define BBATCH 2
#define SSEQ 2048
#define DMODEL 1024
#define NH 16
#define MTOT (BBATCH*SSEQ)   // 4096

typedef short bfrag __attribute__((ext_vector_type(8)));   // 8 bf16 (4 VGPRs)
typedef float ffrag __attribute__((ext_vector_type(4)));   // 4 fp32 acc

typedef const __attribute__((address_space(1))) unsigned int* gas_t;
typedef __attribute__((address_space(3))) unsigned int* las_t;

// global -> LDS direct load, 16 B per lane (wave-uniform LDS base + lane*16).
__device__ __forceinline__ void dl16(const void* g, void* l) {
  __builtin_amdgcn_global_load_lds((gas_t)(unsigned long long)g,
                                   (las_t)(unsigned int)(unsigned long long)l,
                                   16, 0, 0);
}

// Explicit LDS-DMA drain before barriers (r6 race fix): CK-style wait, THEN barrier.
__device__ __forceinline__ void drain_vm() {
  asm volatile("s_waitcnt vmcnt(0)" ::: "memory");
}

// Raw v_exp_f32 via BUILTIN (not inline asm — r10 lesson: the compiler's
// hazard recognizer must see the trans-op to insert its wait state).
#if defined(__has_builtin) && __has_builtin(__builtin_amdgcn_exp2f)
__device__ __forceinline__ float fexp2(float x) { return __builtin_amdgcn_exp2f(x); }
#else
__device__ __forceinline__ float fexp2(float x) { return exp2f(x); }
#endif

__device__ __forceinline__ unsigned short f2bf(float f) {
  union { float f; unsigned u; } v; v.f = f;
  unsigned r = v.u + 0x7fffu + ((v.u >> 16) & 1u);   // RNE
  return (unsigned short)(r >> 16);
}

// Convert two float4 (8 consecutive fp32) to a bf16 A-fragment (RNE).
__device__ __forceinline__ bfrag cvt_a_bf16(float4 x0, float4 x1) {
  union { __hip_bfloat162 h[4]; bfrag f; } u;
  float2 t0; t0.x = x0.x; t0.y = x0.y;
  float2 t1; t1.x = x0.z; t1.y = x0.w;
  float2 t2; t2.x = x1.x; t2.y = x1.y;
  float2 t3; t3.x = x1.z; t3.y = x1.w;
  u.h[0] = __float22bfloat162_rn(t0);
  u.h[1] = __float22bfloat162_rn(t1);
  u.h[2] = __float22bfloat162_rn(t2);
  u.h[3] = __float22bfloat162_rn(t3);
  return u.f;
}

// ---------------------------------------------------------------------------
// Convert ONLY the weights Wq,Wk,Wv,Wo (fp32) to bf16: [wq][wk][wv][wo].
// ---------------------------------------------------------------------------
__global__ __launch_bounds__(256) void convert_w_kernel(
    const float* __restrict__ wq, const float* __restrict__ wk,
    const float* __restrict__ wv, const float* __restrict__ wo,
    unsigned short* __restrict__ dst)
{
  const long NW = (long)DMODEL * DMODEL;   // 1M = 2^20
  const long total8 = (4 * NW) >> 3;
  long i8 = (long)blockIdx.x * blockDim.x + threadIdx.x;
  const long stride = (long)gridDim.x * blockDim.x;
  for (; i8 < total8; i8 += stride) {
    const long i = i8 << 3;
    const int wsel = (int)(i >> 20);
    const long off = i & (NW - 1);
    const float* src = (wsel == 0) ? wq : (wsel == 1) ? wk : (wsel == 2) ? wv : wo;
    const float4 x0 = *(const float4*)(src + off);
    const float4 x1 = *(const float4*)(src + off + 4);
    ushort4 o0, o1;
    o0.x = f2bf(x0.x); o0.y = f2bf(x0.y); o0.z = f2bf(x0.z); o0.w = f2bf(x0.w);
    o1.x = f2bf(x1.x); o1.y = f2bf(x1.y); o1.z = f2bf(x1.z); o1.w = f2bf(x1.w);
    union { ushort4 s[2]; uint4 u; } pk; pk.s[0] = o0; pk.s[1] = o1;
    *(uint4*)(dst + i) = pk.u;
  }
}

// ---------------------------------------------------------------------------
// QKV projection: tile 128x128, BK=64. A (fp32 inputs) read per-lane from
// global with a ONE-K-STEP REGISTER PREFETCH (r11 lesson: same-iteration
// direct loads leave full memory latency on the MFMA critical path ->
// MfmaUtil 8%). Pipeline: convert landed raw A -> frags; issue A(kk+1)+B(kk+1)
// prefetch; MFMA. Both prefetches drained by next iteration's drain_vm.
// B (bf16 weights) staged via double-buffered dl16 with XOR chunk swizzle.
// z selects {Q,K,V}. Q/K out: split-head bf16 [B,H,S,64] (Q folds
// 0.125*log2e). V out: transposed bf16 [B,H,64,S].
// ---------------------------------------------------------------------------
struct ProjArgs {
  const float* X[3];
  const unsigned short* W[3];
  const float* bias[3];
  unsigned short* dst[3];
  float scale[3];
};

__global__ __launch_bounds__(256, 2) void qkv_proj(ProjArgs a)
{
  __shared__ alignas(16) unsigned short Bs[2][128 * 64];  // 16 KB x2 (B only)
  const int t = threadIdx.x;
  const int lane = t & 63, w = t >> 6;
  const int quad = lane >> 4, l16 = lane & 15;
  const int m0 = blockIdx.x * 128;
  const int n0 = blockIdx.y * 128;
  const int z = blockIdx.z;
  const float* __restrict__ X = a.X[z];
  const unsigned short* __restrict__ W = a.W[z];
  const int wm = (w & 1) * 64, wn = (w >> 1) * 64;

  int sw[2];
#pragma unroll
  for (int c = 0; c < 2; ++c) sw[c] = (((c * 4 + quad) ^ (l16 & 7)) * 8);

  // per-lane A row bases (lane reads its own MFMA A-frag rows)
  const float* xrow[4];
#pragma unroll
  for (int fi = 0; fi < 4; ++fi)
    xrow[fi] = X + (size_t)(m0 + wm + fi * 16 + l16) * DMODEL + quad * 8;

  ffrag acc[4][4];
#pragma unroll
  for (int i = 0; i < 4; ++i)
#pragma unroll
    for (int j = 0; j < 4; ++j)
#pragma unroll
      for (int e = 0; e < 4; ++e) acc[i][j][e] = 0.f;

  // prologue: stage B K-step 0 (dl16) and load A K-step 0 raw (registers)
#pragma unroll
  for (int i = 0; i < 4; ++i) {
    const int ch = i * 256 + t;
    const int row = ch >> 3, lc = (ch & 7) ^ (row & 7);
    dl16(W + (size_t)(n0 + row) * DMODEL + lc * 8, Bs[0] + ch * 8);
  }
  float4 ar[4][2][2];   // raw fp32 A for the CURRENT k-step: [fi][c][half]
#pragma unroll
  for (int fi = 0; fi < 4; ++fi)
#pragma unroll
    for (int c = 0; c < 2; ++c) {
      ar[fi][c][0] = *(const float4*)(xrow[fi] + c * 32);
      ar[fi][c][1] = *(const float4*)(xrow[fi] + c * 32 + 4);
    }

  for (int kk = 0; kk < 16; ++kk) {
    const int cur = kk & 1;
    drain_vm();        // B dl16 AND A raw loads for this step landed
    __syncthreads();   // all waves' staging landed; prior reads of buf[cur] done

    // convert landed raw A -> bf16 frags (frees ar for the next prefetch)
    bfrag af[4][2];
#pragma unroll
    for (int fi = 0; fi < 4; ++fi)
#pragma unroll
      for (int c = 0; c < 2; ++c)
        af[fi][c] = cvt_a_bf16(ar[fi][c][0], ar[fi][c][1]);

    if (kk < 15) {     // prefetch NEXT k-step: B via dl16, A via reg loads
      const int k1 = (kk + 1) * 64, nxt = cur ^ 1;
#pragma unroll
      for (int i = 0; i < 4; ++i) {
        const int ch = i * 256 + t;
        const int row = ch >> 3, lc = (ch & 7) ^ (row & 7);
        dl16(W + (size_t)(n0 + row) * DMODEL + k1 + lc * 8, Bs[nxt] + ch * 8);
      }
#pragma unroll
      for (int fi = 0; fi < 4; ++fi)
#pragma unroll
        for (int c = 0; c < 2; ++c) {
          ar[fi][c][0] = *(const float4*)(xrow[fi] + k1 + c * 32);
          ar[fi][c][1] = *(const float4*)(xrow[fi] + k1 + c * 32 + 4);
        }
    }

    bfrag bg[4][2];
#pragma unroll
    for (int fi = 0; fi < 4; ++fi)
#pragma unroll
      for (int c = 0; c < 2; ++c)
        bg[fi][c] = *(const bfrag*)&Bs[cur][(wn + fi * 16 + l16) * 64 + sw[c]];
#pragma unroll
    for (int c = 0; c < 2; ++c)
#pragma unroll
      for (int fi = 0; fi < 4; ++fi)
#pragma unroll
        for (int fj = 0; fj < 4; ++fj)
          acc[fi][fj] = __builtin_amdgcn_mfma_f32_16x16x32_bf16(af[fi][c], bg[fj][c], acc[fi][fj], 0, 0, 0);
  }

  const float sc = a.scale[z];
  const float* __restrict__ bias = a.bias[z];
  unsigned short* __restrict__ dst = a.dst[z];
#pragma unroll
  for (int fj = 0; fj < 4; ++fj) {
    const int n = n0 + wn + fj * 16 + l16;
    const float bv = bias[n];
    const int h = n >> 6, dk = n & 63;
    if (z < 2) {   // split-head [B,H,S,64]
#pragma unroll
      for (int fi = 0; fi < 4; ++fi)
#pragma unroll
        for (int r = 0; r < 4; ++r) {
          const int m = m0 + wm + fi * 16 + quad * 4 + r;
          const int b_ = m >> 11, s_ = m & (SSEQ - 1);
          dst[((size_t)(b_ * NH + h) * SSEQ + s_) * 64 + dk] = f2bf((acc[fi][fj][r] + bv) * sc);
        }
    } else {       // V transposed [B,H,64,S]; m-run of 4 -> ushort4
#pragma unroll
      for (int fi = 0; fi < 4; ++fi) {
        const int m = m0 + wm + fi * 16 + quad * 4;
        const int b_ = m >> 11, s_ = m & (SSEQ - 1);
        ushort4 pk;
        pk.x = f2bf(acc[fi][fj][0] + bv);
        pk.y = f2bf(acc[fi][fj][1] + bv);
        pk.z = f2bf(acc[fi][fj][2] + bv);
        pk.w = f2bf(acc[fi][fj][3] + bv);
        *(ushort4*)&dst[((size_t)(b_ * NH + h) * 64 + dk) * SSEQ + s_] = pk;
      }
    }
  }
}

// ---------------------------------------------------------------------------
// Output projection: ctx bf16 [4096,1024] @ Wo^T + bo -> fp32 d_out.
// Tile 128x64 (512 blocks = 2/CU), BK=64, dbuf pipeline, XOR swizzle.
// ---------------------------------------------------------------------------
__global__ __launch_bounds__(256, 2) void out_proj(
    const unsigned short* __restrict__ X,
    const unsigned short* __restrict__ W,
    const float* __restrict__ bias,
    float* __restrict__ Y)
{
  __shared__ alignas(16) unsigned short As[2][128 * 64];  // 32 KB
  __shared__ alignas(16) unsigned short Bs[2][64 * 64];   // 16 KB
  const int t = threadIdx.x;
  const int lane = t & 63, w = t >> 6;
  const int quad = lane >> 4, l16 = lane & 15;
  const int m0 = blockIdx.x * 128;
  const int n0 = blockIdx.y * 64;
  const int wm = (w & 1) * 64, wn = (w >> 1) * 32;

  int sw[2];
#pragma unroll
  for (int c = 0; c < 2; ++c) sw[c] = (((c * 4 + quad) ^ (l16 & 7)) * 8);

  ffrag acc[4][2];
#pragma unroll
  for (int i = 0; i < 4; ++i)
#pragma unroll
    for (int j = 0; j < 2; ++j)
#pragma unroll
      for (int e = 0; e < 4; ++e) acc[i][j][e] = 0.f;

#pragma unroll
  for (int i = 0; i < 4; ++i) {
    const int ch = i * 256 + t;
    const int row = ch >> 3, lc = (ch & 7) ^ (row & 7);
    dl16(X + (size_t)(m0 + row) * DMODEL + lc * 8, As[0] + ch * 8);
  }
#pragma unroll
  for (int i = 0; i < 2; ++i) {
    const int ch = i * 256 + t;
    const int row = ch >> 3, lc = (ch & 7) ^ (row & 7);
    dl16(W + (size_t)(n0 + row) * DMODEL + lc * 8, Bs[0] + ch * 8);
  }

  for (int kk = 0; kk < 16; ++kk) {
    const int cur = kk & 1;
    drain_vm();
    __syncthreads();

    if (kk < 15) {
      const int k1 = (kk + 1) * 64, nxt = cur ^ 1;
#pragma unroll
      for (int i = 0; i < 4; ++i) {
        const int ch = i * 256 + t;
        const int row = ch >> 3, lc = (ch & 7) ^ (row & 7);
        dl16(X + (size_t)(m0 + row) * DMODEL + k1 + lc * 8, As[nxt] + ch * 8);
      }
#pragma unroll
      for (int i = 0; i < 2; ++i) {
        const int ch = i * 256 + t;
        const int row = ch >> 3, lc = (ch & 7) ^ (row & 7);
        dl16(W + (size_t)(n0 + row) * DMODEL + k1 + lc * 8, Bs[nxt] + ch * 8);
      }
    }

    bfrag af[4][2], bg[2][2];
#pragma unroll
    for (int fi = 0; fi < 4; ++fi)
#pragma unroll
      for (int c = 0; c < 2; ++c)
        af[fi][c] = *(const bfrag*)&As[cur][(wm + fi * 16 + l16) * 64 + sw[c]];
#pragma unroll
    for (int fj = 0; fj < 2; ++fj)
#pragma unroll
      for (int c = 0; c < 2; ++c)
        bg[fj][c] = *(const bfrag*)&Bs[cur][(wn + fj * 16 + l16) * 64 + sw[c]];
#pragma unroll
    for (int c = 0; c < 2; ++c)
#pragma unroll
      for (int fi = 0; fi < 4; ++fi)
#pragma unroll
        for (int fj = 0; fj < 2; ++fj)
          acc[fi][fj] = __builtin_amdgcn_mfma_f32_16x16x32_bf16(af[fi][c], bg[fj][c], acc[fi][fj], 0, 0, 0);
  }

#pragma unroll
  for (int fj = 0; fj < 2; ++fj) {
    const int n = n0 + wn + fj * 16 + l16;
    const float bv = bias[n];
#pragma unroll
    for (int fi = 0; fi < 4; ++fi)
#pragma unroll
      for (int r = 0; r < 4; ++r) {
        const int m = m0 + wm + fi * 16 + quad * 4 + r;
        Y[(size_t)m * DMODEL + n] = acc[fi][fj][r] + bv;
      }
  }
}

// ---------------------------------------------------------------------------
// Flash attention (64-q blocks, 4 waves, 1024 blocks = 4/CU). No-max softmax,
// S^T/O^T orientation, Q pre-scaled by 0.125*log2e; exp via builtin exp2.
// Row-sum l via MFMA with A=ones. K-loop split body/diagonal. Dbuf staging,
// one barrier/tile, explicit drain_vm, XOR chunk swizzle. LDS = 40 KB.
// ---------------------------------------------------------------------------
__global__ __launch_bounds__(256, 4) void attn_mfma(
    const unsigned short* __restrict__ Q,    // [B,H,S,64]
    const unsigned short* __restrict__ K,    // [B,H,S,64]
    const unsigned short* __restrict__ Vt_g, // [B,H,64,S]  (transposed)
    unsigned short* __restrict__ ctx)        // [B*S, 1024]
{
  __shared__ alignas(16) unsigned short Kb[2][64 * 64];  // [key][dk], swizzled
  __shared__ alignas(16) unsigned short Vb[2][64 * 64];  // [dk][key], swizzled
  __shared__ alignas(16) unsigned short Pt[4][16 * 64];  // per-wave [q][key], swizzled

  const int t = threadIdx.x;
  const int lane = t & 63, w = t >> 6;
  const int quad = lane >> 4, l16 = lane & 15;
  const int bh = blockIdx.y;
  const int qtile = blockIdx.z ? (31 - (int)blockIdx.x) : (int)blockIdx.x;
  const int i0 = qtile * 64;
  const int b_ = bh >> 4, h_ = bh & (NH - 1);
  const int q_l = w * 16 + l16;

  const unsigned short* kg = K + (size_t)bh * SSEQ * 64;
  const unsigned short* vg = Vt_g + (size_t)bh * 64 * SSEQ;

  // per-thread staging constants (2 chunks of 16 B each for K and V)
  int koff[2], voff[2], loff[2];
#pragma unroll
  for (int i = 0; i < 2; ++i) {
    const int ch = i * 256 + t;
    const int r = ch >> 3;
    const int lc = (ch & 7) ^ (r & 7);    // logical chunk for this physical slot
    koff[i] = r * 64 + lc * 8;            // K: row=key, col=dk
    voff[i] = r * SSEQ + lc * 8;          // V: row=dk, col=key (global stride S)
    loff[i] = ch * 8;                     // linear LDS dest (dl16 requirement)
  }
  int sw[2];
#pragma unroll
  for (int c = 0; c < 2; ++c) sw[c] = (((c * 4 + quad) ^ (l16 & 7)) * 8);
  const int pwr = l16 * 64 + (quad & 1) * 4;   // Pt write: row part + intra-chunk

  // prologue: stage tile 0 into buffer 0
#pragma unroll
  for (int i = 0; i < 2; ++i) {
    dl16(kg + koff[i], Kb[0] + loff[i]);
    dl16(vg + voff[i], Vb[0] + loff[i]);
  }

  // Q B-frags straight from global (read once): B[n=q][k=dk]
  const unsigned short* qg = Q + ((size_t)bh * SSEQ + i0) * 64;
  bfrag qb[2];
#pragma unroll
  for (int c = 0; c < 2; ++c)
    qb[c] = *(const bfrag*)(qg + (size_t)q_l * 64 + c * 32 + quad * 8);

  bfrag onesf;
#pragma unroll
  for (int j = 0; j < 8; ++j) onesf[j] = (short)0x3F80;   // bf16 1.0

  ffrag o[4], lacc;
#pragma unroll
  for (int fn = 0; fn < 4; ++fn)
#pragma unroll
    for (int e = 0; e < 4; ++e) o[fn][e] = 0.f;
#pragma unroll
  for (int e = 0; e < 4; ++e) lacc[e] = 0.f;

  for (int jt = 0; jt < qtile + 1; ++jt) {
    const int cur = jt & 1;
    const bool diag = (jt == qtile);
    drain_vm();        // own dl16s (prologue / prev-iter prefetch) landed
    __syncthreads();   // all waves' staging landed; prev reads of buf[cur] done

    if (!diag) {       // prefetch next tile into the other buffer
      const int nxt = cur ^ 1;
#pragma unroll
      for (int i = 0; i < 2; ++i) {
        dl16(kg + (size_t)(jt + 1) * 4096 + koff[i], Kb[nxt] + loff[i]);
        dl16(vg + (size_t)(jt + 1) * 64   + voff[i], Vb[nxt] + loff[i]);
      }
    }

    // S^T = K.Q^T : D[m=key][n=q]
    ffrag s[4];
#pragma unroll
    for (int fj = 0; fj < 4; ++fj)
#pragma unroll
      for (int e = 0; e < 4; ++e) s[fj][e] = 0.f;
#pragma unroll
    for (int c = 0; c < 2; ++c)
#pragma unroll
      for (int fj = 0; fj < 4; ++fj) {
        bfrag ka = *(const bfrag*)&Kb[cur][(fj * 16 + l16) * 64 + sw[c]];
        s[fj] = __builtin_amdgcn_mfma_f32_16x16x32_bf16(ka, qb[c], s[fj], 0, 0, 0);
      }

    // softmax (no max subtraction) + pack to bf16 + store P[q][key] swizzled.
    if (diag) {
#pragma unroll
      for (int fj = 0; fj < 4; ++fj) {
        float p[4];
#pragma unroll
        for (int r = 0; r < 4; ++r) {
          const float pe = fexp2(s[fj][r]);
          p[r] = ((fj * 16 + quad * 4 + r) > q_l) ? 0.f : pe;   // causal
        }
        float2 lo; lo.x = p[0]; lo.y = p[1];
        float2 hi; hi.x = p[2]; hi.y = p[3];
        union { __hip_bfloat162 h[2]; unsigned long long u; } cv;
        cv.h[0] = __float22bfloat162_rn(lo);
        cv.h[1] = __float22bfloat162_rn(hi);
        const int cc = fj * 2 + (quad >> 1);
        *(unsigned long long*)&Pt[w][pwr + ((cc ^ (l16 & 7)) * 8)] = cv.u;
      }
    } else {
#pragma unroll
      for (int fj = 0; fj < 4; ++fj) {
        float2 lo; lo.x = fexp2(s[fj][0]); lo.y = fexp2(s[fj][1]);
        float2 hi; hi.x = fexp2(s[fj][2]); hi.y = fexp2(s[fj][3]);
        union { __hip_bfloat162 h[2]; unsigned long long u; } cv;
        cv.h[0] = __float22bfloat162_rn(lo);
        cv.h[1] = __float22bfloat162_rn(hi);
        const int cc = fj * 2 + (quad >> 1);
        *(unsigned long long*)&Pt[w][pwr + ((cc ^ (l16 & 7)) * 8)] = cv.u;
      }
    }
    asm volatile("s_waitcnt lgkmcnt(0)" ::: "memory");  // wave-private P RAW

    // O^T += V^T.P (D[m=dk][n=q]); l += ones.P (row sums, all lanes alike)
#pragma unroll
    for (int c = 0; c < 2; ++c) {
      bfrag pb = *(const bfrag*)&Pt[w][l16 * 64 + sw[c]];
      lacc = __builtin_amdgcn_mfma_f32_16x16x32_bf16(onesf, pb, lacc, 0, 0, 0);
#pragma unroll
      for (int fn = 0; fn < 4; ++fn) {
        bfrag va = *(const bfrag*)&Vb[cur][(fn * 16 + l16) * 64 + sw[c]];
        o[fn] = __builtin_amdgcn_mfma_f32_16x16x32_bf16(va, pb, o[fn], 0, 0, 0);
      }
    }
  }

  // epilogue: lane owns q=q_l; every lane's lacc[e] is the full row sum.
  const float inv = 1.f / lacc[0];
  unsigned short* cbase = ctx + (size_t)(b_ * SSEQ + i0 + q_l) * DMODEL + h_ * 64;
#pragma unroll
  for (int fn = 0; fn < 4; ++fn) {
    float2 lo; lo.x = o[fn][0] * inv; lo.y = o[fn][1] * inv;
    float2 hi; hi.x = o[fn][2] * inv; hi.y = o[fn][3] * inv;
    union { __hip_bfloat162 h[2]; unsigned long long u; } cv;
    cv.h[0] = __float22bfloat162_rn(lo);
    cv.h[1] = __float22bfloat162_rn(hi);
    *(unsigned long long*)(cbase + fn * 16 + quad * 4) = cv.u;
  }
}

// ---------------------------------------------------------------------------
extern "C" void kernel_launch(void* const* d_in, const int* in_sizes, int n_in,
                              void* d_out, int out_size, void* d_ws, size_t ws_size,
                              hipStream_t stream)
{
  const float* q  = (const float*)d_in[0];
  const float* k  = (const float*)d_in[1];
  const float* v  = (const float*)d_in[2];
  // d_in[3] = mask (causal tril) — applied analytically
  const float* wq = (const float*)d_in[4];
  const float* bq = (const float*)d_in[5];
  const float* wk = (const float*)d_in[6];
  const float* bk = (const float*)d_in[7];
  const float* wv = (const float*)d_in[8];
  const float* bv = (const float*)d_in[9];
  const float* wo = (const float*)d_in[10];
  const float* bo = (const float*)d_in[11];

  const long NIN = (long)MTOT * DMODEL;   // 4M elems
  const long NW  = (long)DMODEL * DMODEL; // 1M elems
  unsigned short* ws16 = (unsigned short*)d_ws;
  unsigned short* wqb = ws16;        // bf16 weights
  unsigned short* wkb = wqb + NW;
  unsigned short* wvb = wkb + NW;
  unsigned short* wob = wvb + NW;
  unsigned short* Qp  = wob + NW;    // [B,H,S,64] bf16, pre-scaled
  unsigned short* Kp  = Qp + NIN;    // [B,H,S,64]
  unsigned short* Vp  = Kp + NIN;    // [B,H,64,S] (transposed)
  unsigned short* Cx  = Vp + NIN;    // ctx [B*S,1024]
  // total = 20M shorts = 40 MB

  convert_w_kernel<<<1024, 256, 0, stream>>>(wq, wk, wv, wo, ws16);

  ProjArgs pa;
  pa.X[0] = q;   pa.X[1] = k;   pa.X[2] = v;     // fp32 inputs, read direct
  pa.W[0] = wqb; pa.W[1] = wkb; pa.W[2] = wvb;
  pa.bias[0] = bq; pa.bias[1] = bk; pa.bias[2] = bv;
  pa.dst[0] = Qp; pa.dst[1] = Kp; pa.dst[2] = Vp;
  pa.scale[0] = 0.18033688011112042f;  // 0.125 * log2(e): exp via v_exp_f32
  pa.scale[1] = 1.0f;
  pa.scale[2] = 1.0f;
  qkv_proj<<<dim3(MTOT / 128, DMODEL / 128, 3), 256, 0, stream>>>(pa);

  attn_mfma<<<dim3(16, BBATCH * NH, 2), 256, 0, stream>>>(Qp, Kp, Vp, Cx);

  out_proj<<<dim3(MTOT / 128, DMODEL / 64), 256, 0, stream>>>(Cx, wob, bo, (float*)d_out);
}

// Round 13
// 219.259 us; speedup vs baseline: 1.3703x; 1.3703x over previous
//
#include <hip/hip_runtime.h>
#include <hip/hip_bf16.h>
#include <math.h>

#define BBATCH 2
#define SSEQ 2048
#define DMODEL 1024
#define NH 16
#define MTOT (BBATCH*SSEQ)   // 4096

typedef short bfrag __attribute__((ext_vector_type(8)));   // 8 bf16 (4 VGPRs)
typedef float ffrag __attribute__((ext_vector_type(4)));   // 4 fp32 acc

typedef const __attribute__((address_space(1))) unsigned int* gas_t;
typedef __attribute__((address_space(3))) unsigned int* las_t;

// global -> LDS direct load, 16 B per lane (wave-uniform LDS base + lane*16).
__device__ __forceinline__ void dl16(const void* g, void* l) {
  __builtin_amdgcn_global_load_lds((gas_t)(unsigned long long)g,
                                   (las_t)(unsigned int)(unsigned long long)l,
                                   16, 0, 0);
}

// Explicit LDS-DMA drain before barriers (r6 race fix): CK-style wait, THEN barrier.
__device__ __forceinline__ void drain_vm() {
  asm volatile("s_waitcnt vmcnt(0)" ::: "memory");
}

// Raw v_exp_f32 via BUILTIN (r10 lesson: inline asm hides the trans-op from
// the hazard recognizer -> stale-register corruption; builtin is safe and
// validated correct in r11/r12).
#if defined(__has_builtin) && __has_builtin(__builtin_amdgcn_exp2f)
__device__ __forceinline__ float fexp2(float x) { return __builtin_amdgcn_exp2f(x); }
#else
__device__ __forceinline__ float fexp2(float x) { return exp2f(x); }
#endif

__device__ __forceinline__ unsigned short f2bf(float f) {
  union { float f; unsigned u; } v; v.f = f;
  unsigned r = v.u + 0x7fffu + ((v.u >> 16) & 1u);   // RNE
  return (unsigned short)(r >> 16);
}

// ---------------------------------------------------------------------------
// Convert q,k,v,Wq,Wk,Wv,Wo (fp32) to bf16 into ws, 16B stores:
// [q 4M][k 4M][v 4M][wq 1M][wk 1M][wv 1M][wo 1M]
// (r12 lesson: direct fp32 A-reads in the GEMM are 4x the bytes + redundant
//  per-wave; the separate convert pass + bf16 dl16 staging is faster.)
// ---------------------------------------------------------------------------
__global__ __launch_bounds__(256) void convert_all_kernel(
    const float* __restrict__ q, const float* __restrict__ k, const float* __restrict__ v,
    const float* __restrict__ wq, const float* __restrict__ wk,
    const float* __restrict__ wv, const float* __restrict__ wo,
    unsigned short* __restrict__ dst)
{
  const long NIN = (long)MTOT * DMODEL;   // 4M
  const long NW  = (long)DMODEL * DMODEL; // 1M = 2^20
  const long total8 = (3 * NIN + 4 * NW) >> 3;
  long i8 = (long)blockIdx.x * blockDim.x + threadIdx.x;
  const long stride = (long)gridDim.x * blockDim.x;
  for (; i8 < total8; i8 += stride) {
    const long i = i8 << 3;
    const float* src; long off;
    if (i < NIN)          { src = q; off = i; }
    else if (i < 2 * NIN) { src = k; off = i - NIN; }
    else if (i < 3 * NIN) { src = v; off = i - 2 * NIN; }
    else {
      const long j = i - 3 * NIN;
      const int wsel = (int)(j >> 20);
      off = j & (NW - 1);
      src = (wsel == 0) ? wq : (wsel == 1) ? wk : (wsel == 2) ? wv : wo;
    }
    const float4 x0 = *(const float4*)(src + off);
    const float4 x1 = *(const float4*)(src + off + 4);
    ushort4 o0, o1;
    o0.x = f2bf(x0.x); o0.y = f2bf(x0.y); o0.z = f2bf(x0.z); o0.w = f2bf(x0.w);
    o1.x = f2bf(x1.x); o1.y = f2bf(x1.y); o1.z = f2bf(x1.z); o1.w = f2bf(x1.w);
    union { ushort4 s[2]; uint4 u; } pk; pk.s[0] = o0; pk.s[1] = o1;
    *(uint4*)(dst + i) = pk.u;
  }
}

// ---------------------------------------------------------------------------
// QKV projection (r9 form — best known): tile 128x128, BK=64, double-buffered
// dl16 pipeline for BOTH A (bf16 inputs) and B (bf16 weights), XOR chunk
// swizzle. z selects {Q,K,V}. Q/K out: split-head bf16 [B,H,S,64] (Q folds
// 0.125*log2e). V out: transposed bf16 [B,H,64,S].
// ---------------------------------------------------------------------------
struct ProjArgs {
  const unsigned short* X[3];
  const unsigned short* W[3];
  const float* bias[3];
  unsigned short* dst[3];
  float scale[3];
};

__global__ __launch_bounds__(256, 2) void qkv_proj(ProjArgs a)
{
  __shared__ alignas(16) unsigned short As[2][128 * 64];  // 32 KB
  __shared__ alignas(16) unsigned short Bs[2][128 * 64];  // 32 KB
  const int t = threadIdx.x;
  const int lane = t & 63, w = t >> 6;
  const int quad = lane >> 4, l16 = lane & 15;
  const int m0 = blockIdx.x * 128;
  const int n0 = blockIdx.y * 128;
  const int z = blockIdx.z;
  const unsigned short* __restrict__ X = a.X[z];
  const unsigned short* __restrict__ W = a.W[z];
  const int wm = (w & 1) * 64, wn = (w >> 1) * 64;

  int sw[2];
#pragma unroll
  for (int c = 0; c < 2; ++c) sw[c] = (((c * 4 + quad) ^ (l16 & 7)) * 8);

  ffrag acc[4][4];
#pragma unroll
  for (int i = 0; i < 4; ++i)
#pragma unroll
    for (int j = 0; j < 4; ++j)
#pragma unroll
      for (int e = 0; e < 4; ++e) acc[i][j][e] = 0.f;

  // prologue: stage K-step 0 into buffer 0 (source col swizzled by row)
#pragma unroll
  for (int i = 0; i < 4; ++i) {
    const int ch = i * 256 + t;
    const int row = ch >> 3, lc = (ch & 7) ^ (row & 7);
    dl16(X + (size_t)(m0 + row) * DMODEL + lc * 8, As[0] + ch * 8);
    dl16(W + (size_t)(n0 + row) * DMODEL + lc * 8, Bs[0] + ch * 8);
  }

  for (int kk = 0; kk < 16; ++kk) {
    const int cur = kk & 1;
    drain_vm();        // own staging for buf[cur] landed
    __syncthreads();   // all waves' staging landed; prior reads of buf[cur] done

    if (kk < 15) {     // prefetch next K-step into other buffer (overlaps MFMA)
      const int k1 = (kk + 1) * 64, nxt = cur ^ 1;
#pragma unroll
      for (int i = 0; i < 4; ++i) {
        const int ch = i * 256 + t;
        const int row = ch >> 3, lc = (ch & 7) ^ (row & 7);
        dl16(X + (size_t)(m0 + row) * DMODEL + k1 + lc * 8, As[nxt] + ch * 8);
        dl16(W + (size_t)(n0 + row) * DMODEL + k1 + lc * 8, Bs[nxt] + ch * 8);
      }
    }

    bfrag af[4][2], bg[4][2];
#pragma unroll
    for (int fi = 0; fi < 4; ++fi)
#pragma unroll
      for (int c = 0; c < 2; ++c) {
        af[fi][c] = *(const bfrag*)&As[cur][(wm + fi * 16 + l16) * 64 + sw[c]];
        bg[fi][c] = *(const bfrag*)&Bs[cur][(wn + fi * 16 + l16) * 64 + sw[c]];
      }
#pragma unroll
    for (int c = 0; c < 2; ++c)
#pragma unroll
      for (int fi = 0; fi < 4; ++fi)
#pragma unroll
        for (int fj = 0; fj < 4; ++fj)
          acc[fi][fj] = __builtin_amdgcn_mfma_f32_16x16x32_bf16(af[fi][c], bg[fj][c], acc[fi][fj], 0, 0, 0);
  }

  const float sc = a.scale[z];
  const float* __restrict__ bias = a.bias[z];
  unsigned short* __restrict__ dst = a.dst[z];
#pragma unroll
  for (int fj = 0; fj < 4; ++fj) {
    const int n = n0 + wn + fj * 16 + l16;
    const float bv = bias[n];
    const int h = n >> 6, dk = n & 63;
    if (z < 2) {   // split-head [B,H,S,64]
#pragma unroll
      for (int fi = 0; fi < 4; ++fi)
#pragma unroll
        for (int r = 0; r < 4; ++r) {
          const int m = m0 + wm + fi * 16 + quad * 4 + r;
          const int b_ = m >> 11, s_ = m & (SSEQ - 1);
          dst[((size_t)(b_ * NH + h) * SSEQ + s_) * 64 + dk] = f2bf((acc[fi][fj][r] + bv) * sc);
        }
    } else {       // V transposed [B,H,64,S]; m-run of 4 -> ushort4
#pragma unroll
      for (int fi = 0; fi < 4; ++fi) {
        const int m = m0 + wm + fi * 16 + quad * 4;
        const int b_ = m >> 11, s_ = m & (SSEQ - 1);
        ushort4 pk;
        pk.x = f2bf(acc[fi][fj][0] + bv);
        pk.y = f2bf(acc[fi][fj][1] + bv);
        pk.z = f2bf(acc[fi][fj][2] + bv);
        pk.w = f2bf(acc[fi][fj][3] + bv);
        *(ushort4*)&dst[((size_t)(b_ * NH + h) * 64 + dk) * SSEQ + s_] = pk;
      }
    }
  }
}

// ---------------------------------------------------------------------------
// Output projection: ctx bf16 [4096,1024] @ Wo^T + bo -> fp32 d_out.
// Tile 128x64 (512 blocks = 2/CU), BK=64, dbuf pipeline, XOR swizzle.
// ---------------------------------------------------------------------------
__global__ __launch_bounds__(256, 2) void out_proj(
    const unsigned short* __restrict__ X,
    const unsigned short* __restrict__ W,
    const float* __restrict__ bias,
    float* __restrict__ Y)
{
  __shared__ alignas(16) unsigned short As[2][128 * 64];  // 32 KB
  __shared__ alignas(16) unsigned short Bs[2][64 * 64];   // 16 KB
  const int t = threadIdx.x;
  const int lane = t & 63, w = t >> 6;
  const int quad = lane >> 4, l16 = lane & 15;
  const int m0 = blockIdx.x * 128;
  const int n0 = blockIdx.y * 64;
  const int wm = (w & 1) * 64, wn = (w >> 1) * 32;

  int sw[2];
#pragma unroll
  for (int c = 0; c < 2; ++c) sw[c] = (((c * 4 + quad) ^ (l16 & 7)) * 8);

  ffrag acc[4][2];
#pragma unroll
  for (int i = 0; i < 4; ++i)
#pragma unroll
    for (int j = 0; j < 2; ++j)
#pragma unroll
      for (int e = 0; e < 4; ++e) acc[i][j][e] = 0.f;

#pragma unroll
  for (int i = 0; i < 4; ++i) {
    const int ch = i * 256 + t;
    const int row = ch >> 3, lc = (ch & 7) ^ (row & 7);
    dl16(X + (size_t)(m0 + row) * DMODEL + lc * 8, As[0] + ch * 8);
  }
#pragma unroll
  for (int i = 0; i < 2; ++i) {
    const int ch = i * 256 + t;
    const int row = ch >> 3, lc = (ch & 7) ^ (row & 7);
    dl16(W + (size_t)(n0 + row) * DMODEL + lc * 8, Bs[0] + ch * 8);
  }

  for (int kk = 0; kk < 16; ++kk) {
    const int cur = kk & 1;
    drain_vm();
    __syncthreads();

    if (kk < 15) {
      const int k1 = (kk + 1) * 64, nxt = cur ^ 1;
#pragma unroll
      for (int i = 0; i < 4; ++i) {
        const int ch = i * 256 + t;
        const int row = ch >> 3, lc = (ch & 7) ^ (row & 7);
        dl16(X + (size_t)(m0 + row) * DMODEL + k1 + lc * 8, As[nxt] + ch * 8);
      }
#pragma unroll
      for (int i = 0; i < 2; ++i) {
        const int ch = i * 256 + t;
        const int row = ch >> 3, lc = (ch & 7) ^ (row & 7);
        dl16(W + (size_t)(n0 + row) * DMODEL + k1 + lc * 8, Bs[nxt] + ch * 8);
      }
    }

    bfrag af[4][2], bg[2][2];
#pragma unroll
    for (int fi = 0; fi < 4; ++fi)
#pragma unroll
      for (int c = 0; c < 2; ++c)
        af[fi][c] = *(const bfrag*)&As[cur][(wm + fi * 16 + l16) * 64 + sw[c]];
#pragma unroll
    for (int fj = 0; fj < 2; ++fj)
#pragma unroll
      for (int c = 0; c < 2; ++c)
        bg[fj][c] = *(const bfrag*)&Bs[cur][(wn + fj * 16 + l16) * 64 + sw[c]];
#pragma unroll
    for (int c = 0; c < 2; ++c)
#pragma unroll
      for (int fi = 0; fi < 4; ++fi)
#pragma unroll
        for (int fj = 0; fj < 2; ++fj)
          acc[fi][fj] = __builtin_amdgcn_mfma_f32_16x16x32_bf16(af[fi][c], bg[fj][c], acc[fi][fj], 0, 0, 0);
  }

#pragma unroll
  for (int fj = 0; fj < 2; ++fj) {
    const int n = n0 + wn + fj * 16 + l16;
    const float bv = bias[n];
#pragma unroll
    for (int fi = 0; fi < 4; ++fi)
#pragma unroll
      for (int r = 0; r < 4; ++r) {
        const int m = m0 + wm + fi * 16 + quad * 4 + r;
        Y[(size_t)m * DMODEL + n] = acc[fi][fj][r] + bv;
      }
  }
}

// ---------------------------------------------------------------------------
// Flash attention (64-q blocks, 4 waves, 1024 blocks = 4/CU). No-max softmax,
// S^T/O^T orientation, Q pre-scaled by 0.125*log2e; exp via builtin v_exp_f32.
// Row-sum l via MFMA with A=ones. K-loop split body/diagonal. Dbuf staging,
// one barrier/tile, explicit drain_vm, XOR chunk swizzle. LDS = 40 KB.
// ---------------------------------------------------------------------------
__global__ __launch_bounds__(256, 4) void attn_mfma(
    const unsigned short* __restrict__ Q,    // [B,H,S,64]
    const unsigned short* __restrict__ K,    // [B,H,S,64]
    const unsigned short* __restrict__ Vt_g, // [B,H,64,S]  (transposed)
    unsigned short* __restrict__ ctx)        // [B*S, 1024]
{
  __shared__ alignas(16) unsigned short Kb[2][64 * 64];  // [key][dk], swizzled
  __shared__ alignas(16) unsigned short Vb[2][64 * 64];  // [dk][key], swizzled
  __shared__ alignas(16) unsigned short Pt[4][16 * 64];  // per-wave [q][key], swizzled

  const int t = threadIdx.x;
  const int lane = t & 63, w = t >> 6;
  const int quad = lane >> 4, l16 = lane & 15;
  const int bh = blockIdx.y;
  const int qtile = blockIdx.z ? (31 - (int)blockIdx.x) : (int)blockIdx.x;
  const int i0 = qtile * 64;
  const int b_ = bh >> 4, h_ = bh & (NH - 1);
  const int q_l = w * 16 + l16;

  const unsigned short* kg = K + (size_t)bh * SSEQ * 64;
  const unsigned short* vg = Vt_g + (size_t)bh * 64 * SSEQ;

  // per-thread staging constants (2 chunks of 16 B each for K and V)
  int koff[2], voff[2], loff[2];
#pragma unroll
  for (int i = 0; i < 2; ++i) {
    const int ch = i * 256 + t;
    const int r = ch >> 3;
    const int lc = (ch & 7) ^ (r & 7);    // logical chunk for this physical slot
    koff[i] = r * 64 + lc * 8;            // K: row=key, col=dk
    voff[i] = r * SSEQ + lc * 8;          // V: row=dk, col=key (global stride S)
    loff[i] = ch * 8;                     // linear LDS dest (dl16 requirement)
  }
  int sw[2];
#pragma unroll
  for (int c = 0; c < 2; ++c) sw[c] = (((c * 4 + quad) ^ (l16 & 7)) * 8);
  const int pwr = l16 * 64 + (quad & 1) * 4;   // Pt write: row part + intra-chunk

  // prologue: stage tile 0 into buffer 0
#pragma unroll
  for (int i = 0; i < 2; ++i) {
    dl16(kg + koff[i], Kb[0] + loff[i]);
    dl16(vg + voff[i], Vb[0] + loff[i]);
  }

  // Q B-frags straight from global (read once): B[n=q][k=dk]
  const unsigned short* qg = Q + ((size_t)bh * SSEQ + i0) * 64;
  bfrag qb[2];
#pragma unroll
  for (int c = 0; c < 2; ++c)
    qb[c] = *(const bfrag*)(qg + (size_t)q_l * 64 + c * 32 + quad * 8);

  bfrag onesf;
#pragma unroll
  for (int j = 0; j < 8; ++j) onesf[j] = (short)0x3F80;   // bf16 1.0

  ffrag o[4], lacc;
#pragma unroll
  for (int fn = 0; fn < 4; ++fn)
#pragma unroll
    for (int e = 0; e < 4; ++e) o[fn][e] = 0.f;
#pragma unroll
  for (int e = 0; e < 4; ++e) lacc[e] = 0.f;

  for (int jt = 0; jt < qtile + 1; ++jt) {
    const int cur = jt & 1;
    const bool diag = (jt == qtile);
    drain_vm();        // own dl16s (prologue / prev-iter prefetch) landed
    __syncthreads();   // all waves' staging landed; prev reads of buf[cur] done

    if (!diag) {       // prefetch next tile into the other buffer
      const int nxt = cur ^ 1;
#pragma unroll
      for (int i = 0; i < 2; ++i) {
        dl16(kg + (size_t)(jt + 1) * 4096 + koff[i], Kb[nxt] + loff[i]);
        dl16(vg + (size_t)(jt + 1) * 64   + voff[i], Vb[nxt] + loff[i]);
      }
    }

    // S^T = K.Q^T : D[m=key][n=q]
    ffrag s[4];
#pragma unroll
    for (int fj = 0; fj < 4; ++fj)
#pragma unroll
      for (int e = 0; e < 4; ++e) s[fj][e] = 0.f;
#pragma unroll
    for (int c = 0; c < 2; ++c)
#pragma unroll
      for (int fj = 0; fj < 4; ++fj) {
        bfrag ka = *(const bfrag*)&Kb[cur][(fj * 16 + l16) * 64 + sw[c]];
        s[fj] = __builtin_amdgcn_mfma_f32_16x16x32_bf16(ka, qb[c], s[fj], 0, 0, 0);
      }

    // softmax (no max subtraction) + pack to bf16 + store P[q][key] swizzled.
    // Masked elements stored as 0 -> excluded from both O and l automatically.
    if (diag) {
#pragma unroll
      for (int fj = 0; fj < 4; ++fj) {
        float p[4];
#pragma unroll
        for (int r = 0; r < 4; ++r) {
          const float pe = fexp2(s[fj][r]);
          p[r] = ((fj * 16 + quad * 4 + r) > q_l) ? 0.f : pe;   // causal
        }
        float2 lo; lo.x = p[0]; lo.y = p[1];
        float2 hi; hi.x = p[2]; hi.y = p[3];
        union { __hip_bfloat162 h[2]; unsigned long long u; } cv;
        cv.h[0] = __float22bfloat162_rn(lo);
        cv.h[1] = __float22bfloat162_rn(hi);
        const int cc = fj * 2 + (quad >> 1);
        *(unsigned long long*)&Pt[w][pwr + ((cc ^ (l16 & 7)) * 8)] = cv.u;
      }
    } else {
#pragma unroll
      for (int fj = 0; fj < 4; ++fj) {
        float2 lo; lo.x = fexp2(s[fj][0]); lo.y = fexp2(s[fj][1]);
        float2 hi; hi.x = fexp2(s[fj][2]); hi.y = fexp2(s[fj][3]);
        union { __hip_bfloat162 h[2]; unsigned long long u; } cv;
        cv.h[0] = __float22bfloat162_rn(lo);
        cv.h[1] = __float22bfloat162_rn(hi);
        const int cc = fj * 2 + (quad >> 1);
        *(unsigned long long*)&Pt[w][pwr + ((cc ^ (l16 & 7)) * 8)] = cv.u;
      }
    }
    asm volatile("s_waitcnt lgkmcnt(0)" ::: "memory");  // wave-private P RAW

    // O^T += V^T.P (D[m=dk][n=q]); l += ones.P (row sums, all lanes alike)
#pragma unroll
    for (int c = 0; c < 2; ++c) {
      bfrag pb = *(const bfrag*)&Pt[w][l16 * 64 + sw[c]];
      lacc = __builtin_amdgcn_mfma_f32_16x16x32_bf16(onesf, pb, lacc, 0, 0, 0);
#pragma unroll
      for (int fn = 0; fn < 4; ++fn) {
        bfrag va = *(const bfrag*)&Vb[cur][(fn * 16 + l16) * 64 + sw[c]];
        o[fn] = __builtin_amdgcn_mfma_f32_16x16x32_bf16(va, pb, o[fn], 0, 0, 0);
      }
    }
  }

  // epilogue: lane owns q=q_l; every lane's lacc[e] is the full row sum.
  const float inv = 1.f / lacc[0];
  unsigned short* cbase = ctx + (size_t)(b_ * SSEQ + i0 + q_l) * DMODEL + h_ * 64;
#pragma unroll
  for (int fn = 0; fn < 4; ++fn) {
    float2 lo; lo.x = o[fn][0] * inv; lo.y = o[fn][1] * inv;
    float2 hi; hi.x = o[fn][2] * inv; hi.y = o[fn][3] * inv;
    union { __hip_bfloat162 h[2]; unsigned long long u; } cv;
    cv.h[0] = __float22bfloat162_rn(lo);
    cv.h[1] = __float22bfloat162_rn(hi);
    *(unsigned long long*)(cbase + fn * 16 + quad * 4) = cv.u;
  }
}

// ---------------------------------------------------------------------------
extern "C" void kernel_launch(void* const* d_in, const int* in_sizes, int n_in,
                              void* d_out, int out_size, void* d_ws, size_t ws_size,
                              hipStream_t stream)
{
  const float* q  = (const float*)d_in[0];
  const float* k  = (const float*)d_in[1];
  const float* v  = (const float*)d_in[2];
  // d_in[3] = mask (causal tril) — applied analytically
  const float* wq = (const float*)d_in[4];
  const float* bq = (const float*)d_in[5];
  const float* wk = (const float*)d_in[6];
  const float* bk = (const float*)d_in[7];
  const float* wv = (const float*)d_in[8];
  const float* bv = (const float*)d_in[9];
  const float* wo = (const float*)d_in[10];
  const float* bo = (const float*)d_in[11];

  const long NIN = (long)MTOT * DMODEL;   // 4M elems
  const long NW  = (long)DMODEL * DMODEL; // 1M elems
  unsigned short* ws16 = (unsigned short*)d_ws;
  unsigned short* qx  = ws16;
  unsigned short* kx  = qx + NIN;
  unsigned short* vx  = kx + NIN;
  unsigned short* wqb = vx + NIN;
  unsigned short* wkb = wqb + NW;
  unsigned short* wvb = wkb + NW;
  unsigned short* wob = wvb + NW;
  unsigned short* Qp  = wob + NW;   // [B,H,S,64] bf16, pre-scaled
  unsigned short* Kp  = Qp + NIN;   // [B,H,S,64]
  unsigned short* Vp  = Kp + NIN;   // [B,H,64,S] (transposed)
  unsigned short* Cx  = Vp + NIN;   // ctx [B*S,1024]

  convert_all_kernel<<<2048, 256, 0, stream>>>(q, k, v, wq, wk, wv, wo, ws16);

  ProjArgs pa;
  pa.X[0] = qx;  pa.X[1] = kx;  pa.X[2] = vx;
  pa.W[0] = wqb; pa.W[1] = wkb; pa.W[2] = wvb;
  pa.bias[0] = bq; pa.bias[1] = bk; pa.bias[2] = bv;
  pa.dst[0] = Qp; pa.dst[1] = Kp; pa.dst[2] = Vp;
  pa.scale[0] = 0.18033688011112042f;  // 0.125 * log2(e): exp via v_exp_f32
  pa.scale[1] = 1.0f;
  pa.scale[2] = 1.0f;
  qkv_proj<<<dim3(MTOT / 128, DMODEL / 128, 3), 256, 0, stream>>>(pa);

  attn_mfma<<<dim3(16, BBATCH * NH, 2), 256, 0, stream>>>(Qp, Kp, Vp, Cx);

  out_proj<<<dim3(MTOT / 128, DMODEL / 64), 256, 0, stream>>>(Cx, wob, bo, (float*)d_out);
}